// Round 9
// baseline (528.502 us; speedup 1.0000x reference)
//
#include <hip/hip_runtime.h>
#include <math.h>

// Problem constants (reference: VOCAB=10000, HID=256, B=64, T=64)
#define VOCABN 10000
#define HIDN   256
#define GATES  1024   // 4*HID
#define BN     64
#define TN     64
#define BT     4096   // B*T
#define NCT    625    // vocab col-tiles of 16 (10000 = 625*16 exactly)

typedef unsigned int       u32;
typedef unsigned short     u16;
typedef unsigned long long u64;
typedef float v4f __attribute__((ext_vector_type(4)));
typedef short v8s __attribute__((ext_vector_type(8)));

__device__ __forceinline__ float bf2f(u16 u) {
    return __uint_as_float(((u32)u) << 16);
}
__device__ __forceinline__ u16 f2bf(float f) {          // round-to-nearest-even
    u32 u = __float_as_uint(f);
    u += 0x7FFFu + ((u >> 16) & 1u);
    return (u16)(u >> 16);
}
__device__ __forceinline__ float fast_sigmoid(float x) {
    return 1.0f / (1.0f + __expf(-x));
}
__device__ __forceinline__ float fast_tanh(float x) {
    float e = __expf(-2.0f * fabsf(x));
    float t = (1.0f - e) / (1.0f + e);
    return copysignf(t, x);
}
__device__ __forceinline__ u64 llc_load(const u64* p) {
    return __hip_atomic_load(p, __ATOMIC_RELAXED, __HIP_MEMORY_SCOPE_AGENT);
}
__device__ __forceinline__ void llc_store(u64* p, u64 v) {
    __hip_atomic_store(p, v, __ATOMIC_RELAXED, __HIP_MEMORY_SCOPE_AGENT);
}

// ---------------------------------------------------------------------------
// fp32 [HIDN][ncols] tile c -> bf16 MFMA B-fragment layout [c][8 q][64 l][8].
// Fragment (c,q), lane l holds B[k = q*32 + (l>>4)*8 + j][n = c*16 + (l&15)].
// ---------------------------------------------------------------------------
__device__ __forceinline__ void wfrag_dev(
    const float* __restrict__ src, u16* __restrict__ dst, int ncols, int c,
    int t, u16 lt[HIDN][16])
{
    const float* s = src + (size_t)t * ncols + c * 16;
    #pragma unroll
    for (int j4 = 0; j4 < 4; ++j4) {
        float4 v = *(const float4*)(s + j4 * 4);
        lt[t][j4*4+0] = f2bf(v.x);
        lt[t][j4*4+1] = f2bf(v.y);
        lt[t][j4*4+2] = f2bf(v.z);
        lt[t][j4*4+3] = f2bf(v.w);
    }
    __syncthreads();
    #pragma unroll
    for (int h = 0; h < 2; ++h) {
        int f = t + h * 256;             // frag id = q*64 + l
        int q = f >> 6, l = f & 63;
        int m = l & 15, kb = q * 32 + ((l >> 4) & 3) * 8;
        u32 w[4];
        #pragma unroll
        for (int j = 0; j < 4; ++j)
            w[j] = (u32)lt[kb + 2*j][m] | ((u32)lt[kb + 2*j + 1][m] << 16);
        *(uint4*)(dst + (((size_t)c * 8 + q) * 64 + l) * 8) =
            make_uint4(w[0], w[1], w[2], w[3]);
    }
}

// ---------------------------------------------------------------------------
// Prep 1 (753 blocks): all three weight transforms.
//   0..63: W_lstm x-part -> Wxf | 64..127: h-part -> Whf | 128..752: W_dense
// ---------------------------------------------------------------------------
__global__ __launch_bounds__(256) void k_prep1(
    const float* __restrict__ W_lstm,
    const float* __restrict__ W_dense,
    u16* __restrict__ Wxf, u16* __restrict__ Whf, u16* __restrict__ Wf)
{
    __shared__ u16 lt[HIDN][16];
    const int bid = blockIdx.x;
    if (bid < 64)
        wfrag_dev(W_lstm, Wxf, GATES, bid, threadIdx.x, lt);
    else if (bid < 128)
        wfrag_dev(W_lstm + (size_t)HIDN * GATES, Whf, GATES, bid - 64,
                  threadIdx.x, lt);
    else
        wfrag_dev(W_dense, Wf, VOCABN, bid - 128, threadIdx.x, lt);
}

// ---------------------------------------------------------------------------
// Prep 2 (256 blocks): gates_x = E[idx] @ W_x + b_lstm -> bf16.
// ---------------------------------------------------------------------------
__global__ __launch_bounds__(256) void k_prep2(
    const int*   __restrict__ idx,   // [BT]
    const float* __restrict__ E,     // [VOCAB][HIDN]
    const u16*   __restrict__ Wxf,   // [64][8][64][8]
    const float* __restrict__ bl,    // [GATES]
    u16*         __restrict__ gxb)   // [BT][GATES] bf16
{
    const int r0   = blockIdx.x * 16;
    const int tid  = threadIdx.x;
    const int w    = tid >> 6, lane = tid & 63;
    const int m    = lane & 15, quad = lane >> 4;

    v8s a[8];
    {
        const float* e = E + (size_t)idx[r0 + m] * HIDN + quad * 8;
        #pragma unroll
        for (int q = 0; q < 8; ++q) {
            float4 x0 = *(const float4*)(e + q * 32);
            float4 x1 = *(const float4*)(e + q * 32 + 4);
            uint4 t4 = make_uint4(
                (u32)f2bf(x0.x) | ((u32)f2bf(x0.y) << 16),
                (u32)f2bf(x0.z) | ((u32)f2bf(x0.w) << 16),
                (u32)f2bf(x1.x) | ((u32)f2bf(x1.y) << 16),
                (u32)f2bf(x1.z) | ((u32)f2bf(x1.w) << 16));
            a[q] = *(v8s*)&t4;
        }
    }
    for (int c = w; c < GATES / 16; c += 4) {
        v4f acc = {0.f, 0.f, 0.f, 0.f};
        #pragma unroll
        for (int q = 0; q < 8; ++q) {
            v8s b = *(const v8s*)(Wxf + (((size_t)c * 8 + q) * 64 + lane) * 8);
            acc = __builtin_amdgcn_mfma_f32_16x16x32_bf16(a[q], b, acc, 0, 0, 0);
        }
        const int col = c * 16 + m;
        const float bv = bl[col];
        #pragma unroll
        for (int r = 0; r < 4; ++r)   // D: col=lane&15, row=quad*4+r (m89/m91)
            gxb[(size_t)(r0 + quad * 4 + r) * GATES + col] = f2bf(acc[r] + bv);
    }
}

// ---------------------------------------------------------------------------
// Kernel 2 (persistent MFMA LSTM — R5 structure verbatim, 210us floor):
// 64 blocks = 4 row-groups(16 rows) x 16 unit-slices. W_h slice LDS-resident.
// h-exchange through LLC via relaxed agent u64 ops; 16-block counter barrier
// per step (relaxed agent atomicAdd + busy poll). Runs ALONE — overlap with
// dense was tried twice (R7/R8) and slowed this kernel 1.7x.
// ---------------------------------------------------------------------------
__global__ __launch_bounds__(256) void k_plstm(
    const u16*   __restrict__ Whf,   // [64 ct][8][64][8] h-part frags
    const u16*   __restrict__ gxb,   // [BT][GATES] bf16
    u16*                      Hx,    // [2][BN][HIDN] bf16 exchange (LLC)
    u16*         __restrict__ Hb,    // [BT][HIDN] bf16 output
    u32*                      bar)   // counters (stride 64), zeroed per launch
{
    __shared__ uint4 Wl4[4 * 512];       // 32 KB: [ct][8 q][64 l][8] u16
    __shared__ float gl[4][16][16];      // 4 KB gate exchange

    const int tid  = threadIdx.x;
    const int rg   = blockIdx.x >> 4;    // row group: batch rows rg*16..+15
    const int ns   = blockIdx.x & 15;    // unit slice: units ns*16..+15
    const int u0   = ns * 16;
    const int w    = tid >> 6;           // wave = gate type (i,j,f,o)
    const int lane = tid & 63;
    const int m    = lane & 15, kq = lane >> 4;

    {   // load W_h slice: tiles c = w'*16 + ns, 8 KB contiguous each
        const uint4* src = (const uint4*)Whf;
        #pragma unroll
        for (int i = 0; i < 8; ++i) {
            int e  = tid + i * 256;          // [0, 2048)
            int ct = e >> 9, off = e & 511;  // 512 uint4 per tile
            Wl4[e] = src[(size_t)(ct * 16 + ns) * 512 + off];
        }
    }
    {   // zero gate-exchange so t=0 reads 0 for the h@W_h term
        float* g0 = (float*)gl;
        #pragma unroll
        for (int j = 0; j < 4; ++j) g0[tid * 4 + j] = 0.0f;
    }
    __syncthreads();

    const u16* Wl = (const u16*)Wl4;

    const int r = tid >> 4, u = tid & 15;
    const int b = rg * 16 + r;                       // batch row
    const u16* gxp = gxb + (size_t)b * TN * GATES + u0 + u;
    u16* hbp = Hb + (size_t)b * TN * HIDN + u0 + u;
    const int hxw = b * HIDN + u0 + u;               // Hx elem offset (in-buf)
    const int aoff = (rg * 16 + m) * HIDN + kq * 8;  // a-frag elem offset

    float cstate = 0.0f;
    float gr[4], gn[4];
    #pragma unroll
    for (int g = 0; g < 4; ++g) gr[g] = bf2f(gxp[g * 256]);

    for (int t = 0; t < TN; ++t) {
        if (t + 1 < TN) {
            const u16* p = gxp + (size_t)(t + 1) * GATES;
            #pragma unroll
            for (int g = 0; g < 4; ++g) gn[g] = bf2f(p[g * 256]);
        } else {
            #pragma unroll
            for (int g = 0; g < 4; ++g) gn[g] = gr[g];
        }

        if (t > 0) {
            const u64* hsrc = (const u64*)(Hx + (t & 1) * (BN * HIDN) + aoff);
            v4f acc = {0.f, 0.f, 0.f, 0.f};
            #pragma unroll
            for (int q = 0; q < 8; ++q) {
                union { u64 d[2]; v8s v; } av;
                av.d[0] = llc_load(hsrc + q * 8);
                av.d[1] = llc_load(hsrc + q * 8 + 1);
                v8s bf = *(const v8s*)(Wl + ((w * 8 + q) * 64 + lane) * 8);
                acc = __builtin_amdgcn_mfma_f32_16x16x32_bf16(av.v, bf, acc, 0, 0, 0);
            }
            #pragma unroll
            for (int rr = 0; rr < 4; ++rr)   // row = kq*4+rr, col(unit) = m
                gl[w][kq * 4 + rr][m] = acc[rr];
        }
        __syncthreads();

        {   // cell update for (r, u); c stays in a register
            float ai = gl[0][r][u] + gr[0];
            float aj = gl[1][r][u] + gr[1];
            float af = gl[2][r][u] + gr[2];
            float ao = gl[3][r][u] + gr[3];
            float ig = fast_sigmoid(ai);
            float fg = fast_sigmoid(af + 1.0f);      // forget_bias = 1.0
            float og = fast_sigmoid(ao);
            float jt = fast_tanh(aj);
            cstate = fg * cstate + ig * jt;
            float hn = og * fast_tanh(cstate);
            u32 hv = f2bf(hn);
            hbp[(size_t)t * HIDN] = (u16)hv;

            if (t + 1 < TN) {
                u32 p1 = __shfl_down(hv, 1);
                u32 p2 = __shfl_down(hv, 2);
                u32 p3 = __shfl_down(hv, 3);
                if ((tid & 3) == 0) {
                    u64 pk = (u64)(hv | (p1 << 16))
                           | ((u64)(p2 | (p3 << 16)) << 32);
                    u64* dst = (u64*)(Hx + (((t & 1) ^ 1) * (BN * HIDN)) + hxw);
                    llc_store(dst, pk);
                }
            }
        }

        if (t + 1 < TN) {
            __syncthreads();   // per-wave vmcnt(0) before s_barrier: all
                               // publish stores have reached the LLC
            if (tid == 0) {
                __hip_atomic_fetch_add(&bar[rg * 64], 1u, __ATOMIC_RELAXED,
                                       __HIP_MEMORY_SCOPE_AGENT);
                u32 tgt = (u32)(t + 1) * 16u;
                while (__hip_atomic_load(&bar[rg * 64], __ATOMIC_RELAXED,
                                         __HIP_MEMORY_SCOPE_AGENT) < tgt) { }
            }
            __syncthreads();
        }
        #pragma unroll
        for (int g = 0; g < 4; ++g) gr[g] = gn[g];
    }
}

// ---------------------------------------------------------------------------
// Kernel 3 (MFMA dense, XCD-L2-friendly): 256 blocks. Vocab half chosen by
// BIT 2 of blockIdx so (with round-robin blockIdx%8 -> XCD) XCDs 0-3 run
// half 0 and XCDs 4-7 half 1: each XCD's 32 blocks share one 2.56 MB Wf half
// that fits and stays in its 4 MB L2 (R5's mapping streamed 655 MB from LLC).
// Perf-only assumption — wrong mapping just lowers the L2 hit rate (G16-safe).
// Each block: 32 rows, a-frags register-resident, target capture fused.
// ---------------------------------------------------------------------------
__global__ __launch_bounds__(256) void k_dense(
    const u16*   __restrict__ Hb,    // [BT][HIDN] bf16
    const u16*   __restrict__ Wf,    // [625][8][64][8]
    const float* __restrict__ bd,    // [VOCAB]
    const int*   __restrict__ tgt,   // [BT]
    float*       __restrict__ S,     // [2][BT] partial sumexp
    float*       __restrict__ tl)    // [BT] target logit
{
    __shared__ float Sl[32];
    __shared__ int   tg[32];
    const int bid = blockIdx.x;
    const int hv  = (bid >> 2) & 1;                  // XCD-aligned vocab half
    const int rg  = (bid >> 3) * 4 + (bid & 3);      // 0..127
    const int r0  = rg * 32;
    const int tid = threadIdx.x;
    const int w   = tid >> 6, lane = tid & 63;
    const int m   = lane & 15, kq = lane >> 4;

    if (tid < 32) { Sl[tid] = 0.0f; tg[tid] = tgt[r0 + tid]; }

    v8s a[2][8];
    #pragma unroll
    for (int rt = 0; rt < 2; ++rt) {
        const u16* hrow = Hb + (size_t)(r0 + rt * 16 + m) * HIDN + kq * 8;
        #pragma unroll
        for (int q = 0; q < 8; ++q)
            a[rt][q] = *(const v8s*)(hrow + q * 32);
    }
    __syncthreads();

    float s[2][4] = {{0.f,0.f,0.f,0.f},{0.f,0.f,0.f,0.f}};
    const int cbeg = hv ? 313 : 0;
    const int cend = hv ? NCT : 313;
    for (int c = cbeg + w; c < cend; c += 4) {
        v4f acc0 = {0.f,0.f,0.f,0.f};
        v4f acc1 = {0.f,0.f,0.f,0.f};
        #pragma unroll
        for (int q = 0; q < 8; ++q) {
            v8s bq = *(const v8s*)(Wf + (((size_t)c * 8 + q) * 64 + lane) * 8);
            acc0 = __builtin_amdgcn_mfma_f32_16x16x32_bf16(a[0][q], bq, acc0, 0, 0, 0);
            acc1 = __builtin_amdgcn_mfma_f32_16x16x32_bf16(a[1][q], bq, acc1, 0, 0, 0);
        }
        const int col = c * 16 + m;
        const float bv = bd[col];
        #pragma unroll
        for (int rt = 0; rt < 2; ++rt) {
            v4f* ac = rt ? &acc1 : &acc0;
            #pragma unroll
            for (int r = 0; r < 4; ++r) {
                float l = (*ac)[r] + bv;
                int row = rt * 16 + kq * 4 + r;       // row within 32
                if (col == tg[row]) tl[r0 + row] = l; // unique writer
                s[rt][r] += __expf(l);
            }
        }
    }

    #pragma unroll
    for (int rt = 0; rt < 2; ++rt)
        #pragma unroll
        for (int r = 0; r < 4; ++r)
            atomicAdd(&Sl[rt * 16 + kq * 4 + r], s[rt][r]);
    __syncthreads();
    if (tid < 32) S[(size_t)hv * BT + r0 + tid] = Sl[tid];
}

// ---------------------------------------------------------------------------
// Kernel 4: ppl = exp(log(sumexp) - target_logit)
// ---------------------------------------------------------------------------
__global__ __launch_bounds__(256) void k_final(
    const float* __restrict__ S,     // [2][BT]
    const float* __restrict__ tl,    // [BT]
    float*       __restrict__ out)   // [BT]
{
    int i = blockIdx.x * 256 + threadIdx.x;
    out[i] = __expf(__logf(S[i] + S[BT + i]) - tl[i]);
}

// ---------------------------------------------------------------------------
extern "C" void kernel_launch(void* const* d_in, const int* in_sizes, int n_in,
                              void* d_out, int out_size, void* d_ws, size_t ws_size,
                              hipStream_t stream) {
    const int*   input   = (const int*)  d_in[0];   // [B,T]
    const int*   targets = (const int*)  d_in[1];   // [B,T]
    const float* E       = (const float*)d_in[2];   // [VOCAB,HID]
    const float* W_lstm  = (const float*)d_in[3];   // [2H,4H]
    const float* b_lstm  = (const float*)d_in[4];   // [4H]
    const float* W_dense = (const float*)d_in[5];   // [HID,VOCAB]
    const float* b_dense = (const float*)d_in[6];   // [VOCAB]
    float* out = (float*)d_out;                     // [B,T] perplexity

    // Workspace (~16.4 MB; 20 MB proven in earlier rounds):
    //  [0,8M):            gxb bf16 [BT][GATES]
    //  [8M,13.12M):       Wf  bf16 [625][8][64][8]
    //  [13.25M,15.25M):   Hb bf16 [BT][HIDN]
    //  [15.25M,+512K):    Whf (h-part frags)
    //  [15.75M,+512K):    Wxf (x-part frags)
    //  [16.25M,+64K):     Hx bf16 [2][BN][HIDN] exchange
    //  [+64K,+32K):       S fp32 [2][BT]
    //  [+96K,+16K):       tl fp32 [BT]
    //  [+112K,+1K):       bar u32 [4*64] (256B-strided counters)
    char* ws = (char*)d_ws;
    u16*   gxb = (u16*)ws;
    u16*   Wf  = (u16*)(ws + ((size_t)8 << 20));
    u16*   Hb  = (u16*)(ws + ((size_t)13 << 20) + ((size_t)256 << 10));
    u16*   Whf = (u16*)(ws + ((size_t)15 << 20) + ((size_t)256 << 10));
    u16*   Wxf = (u16*)(ws + ((size_t)15 << 20) + ((size_t)768 << 10));
    u16*   Hx  = (u16*)(ws + ((size_t)16 << 20) + ((size_t)256 << 10));
    float* S   = (float*)(ws + ((size_t)16 << 20) + ((size_t)320 << 10));
    float* tl  = (float*)(ws + ((size_t)16 << 20) + ((size_t)352 << 10));
    u32*   bar = (u32*)  (ws + ((size_t)16 << 20) + ((size_t)368 << 10));

    hipMemsetAsync(bar, 0, 1024, stream);
    k_prep1<<<753,      256, 0, stream>>>(W_lstm, W_dense, Wxf, Whf, Wf);
    k_prep2<<<BT / 16,  256, 0, stream>>>(input, E, Wxf, b_lstm, gxb);
    k_plstm<<<64,       256, 0, stream>>>(Whf, gxb, Hx, Hb, bar);
    k_dense<<<256,      256, 0, stream>>>(Hb, Wf, b_dense, targets, S, tl);
    k_final<<<BT / 256, 256, 0, stream>>>(S, tl, out);
}

// Round 10
// 384.837 us; speedup vs baseline: 1.3733x; 1.3733x over previous
//
#include <hip/hip_runtime.h>
#include <math.h>

// Problem constants (reference: VOCAB=10000, HID=256, B=64, T=64)
#define VOCABN 10000
#define HIDN   256
#define GATES  1024   // 4*HID
#define BN     64
#define TN     64
#define BT     4096   // B*T
#define NCT    625    // vocab col-tiles of 16 (10000 = 625*16 exactly)

typedef unsigned int       u32;
typedef unsigned short     u16;
typedef unsigned long long u64;
typedef float v4f __attribute__((ext_vector_type(4)));
typedef short v8s __attribute__((ext_vector_type(8)));

__device__ __forceinline__ float bf2f(u16 u) {
    return __uint_as_float(((u32)u) << 16);
}
__device__ __forceinline__ u16 f2bf(float f) {          // round-to-nearest-even
    u32 u = __float_as_uint(f);
    u += 0x7FFFu + ((u >> 16) & 1u);
    return (u16)(u >> 16);
}
__device__ __forceinline__ float fast_sigmoid(float x) {
    return 1.0f / (1.0f + __expf(-x));
}
__device__ __forceinline__ float fast_tanh(float x) {
    float e = __expf(-2.0f * fabsf(x));
    float t = (1.0f - e) / (1.0f + e);
    return copysignf(t, x);
}
__device__ __forceinline__ u64 llc_load(const u64* p) {
    return __hip_atomic_load(p, __ATOMIC_RELAXED, __HIP_MEMORY_SCOPE_AGENT);
}
__device__ __forceinline__ void llc_store(u64* p, u64 v) {
    __hip_atomic_store(p, v, __ATOMIC_RELAXED, __HIP_MEMORY_SCOPE_AGENT);
}

// ---------------------------------------------------------------------------
// Generic fp32 [HIDN][ncols] -> bf16 MFMA B-fragment layout [ct][8 q][64 l][8].
// Fragment (c,q), lane l holds B[k = q*32 + (l>>4)*8 + j][n = c*16 + (l&15)],
// j=0..7, as 16 contiguous bytes -> b_frag load is a single coalesced b128.
// ---------------------------------------------------------------------------
__global__ __launch_bounds__(256) void k_wfrag(
    const float* __restrict__ src,   // [HIDN][ncols]
    u16*         __restrict__ dst,   // [nct][8][64][8]
    int ncols)
{
    __shared__ u16 lt[HIDN][16];
    const int c = blockIdx.x;
    const int t = threadIdx.x;
    const float* s = src + (size_t)t * ncols + c * 16;
    #pragma unroll
    for (int j4 = 0; j4 < 4; ++j4) {
        float4 v = *(const float4*)(s + j4 * 4);
        lt[t][j4*4+0] = f2bf(v.x);
        lt[t][j4*4+1] = f2bf(v.y);
        lt[t][j4*4+2] = f2bf(v.z);
        lt[t][j4*4+3] = f2bf(v.w);
    }
    __syncthreads();
    #pragma unroll
    for (int h = 0; h < 2; ++h) {
        int f = t + h * 256;             // frag id = q*64 + l
        int q = f >> 6, l = f & 63;
        int m = l & 15, kb = q * 32 + ((l >> 4) & 3) * 8;
        u32 w[4];
        #pragma unroll
        for (int j = 0; j < 4; ++j)
            w[j] = (u32)lt[kb + 2*j][m] | ((u32)lt[kb + 2*j + 1][m] << 16);
        *(uint4*)(dst + (((size_t)c * 8 + q) * 64 + l) * 8) =
            make_uint4(w[0], w[1], w[2], w[3]);
    }
}

// ---------------------------------------------------------------------------
// Kernel 1 (MFMA): gates_x = E[idx] @ W_x + b_lstm. 256 blocks x 16 rows.
// ---------------------------------------------------------------------------
__global__ __launch_bounds__(256) void k_xgates(
    const int*   __restrict__ idx,   // [BT]
    const float* __restrict__ E,     // [VOCAB][HIDN]
    const u16*   __restrict__ Wxf,   // [64][8][64][8]
    const float* __restrict__ bl,    // [GATES]
    float*       __restrict__ gx)    // [BT][GATES]
{
    const int r0   = blockIdx.x * 16;
    const int tid  = threadIdx.x;
    const int w    = tid >> 6, lane = tid & 63;
    const int m    = lane & 15, quad = lane >> 4;

    v8s a[8];
    {
        const float* e = E + (size_t)idx[r0 + m] * HIDN + quad * 8;
        #pragma unroll
        for (int q = 0; q < 8; ++q) {
            float4 x0 = *(const float4*)(e + q * 32);
            float4 x1 = *(const float4*)(e + q * 32 + 4);
            uint4 t4 = make_uint4(
                (u32)f2bf(x0.x) | ((u32)f2bf(x0.y) << 16),
                (u32)f2bf(x0.z) | ((u32)f2bf(x0.w) << 16),
                (u32)f2bf(x1.x) | ((u32)f2bf(x1.y) << 16),
                (u32)f2bf(x1.z) | ((u32)f2bf(x1.w) << 16));
            a[q] = *(v8s*)&t4;
        }
    }

    for (int c = w; c < GATES / 16; c += 4) {
        v4f acc = {0.f, 0.f, 0.f, 0.f};
        #pragma unroll
        for (int q = 0; q < 8; ++q) {
            v8s b = *(const v8s*)(Wxf + (((size_t)c * 8 + q) * 64 + lane) * 8);
            acc = __builtin_amdgcn_mfma_f32_16x16x32_bf16(a[q], b, acc, 0, 0, 0);
        }
        const int col = c * 16 + m;
        const float bv = bl[col];
        #pragma unroll
        for (int r = 0; r < 4; ++r)   // D: col=lane&15, row=quad*4+r (m89/m91)
            gx[(size_t)(r0 + quad * 4 + r) * GATES + col] = acc[r] + bv;
    }
}

// ---------------------------------------------------------------------------
// Kernel 2 (persistent MFMA LSTM — proven 210us config, verbatim): 64 blocks
// = 4 row-groups(16 rows) x 16 unit-slices. W_h slice LDS-resident in B-frag
// layout. Cross-block h-exchange through the LLC ONLY via relaxed agent u64
// ops (no buffer_inv/wbl2). Counter barrier per step: __syncthreads drains
// publish stores (vmcnt(0) before s_barrier), tid0 bumps relaxed LLC counter.
// Runs ALONE — overlapping dense (R7/R8) slowed this kernel 1.7x.
// ---------------------------------------------------------------------------
__global__ __launch_bounds__(256) void k_plstm(
    const u16*   __restrict__ Whf,   // [64 ct][8][64][8] h-part frags
    const float* __restrict__ gx,    // [BT][GATES]
    u16*                      Hx,    // [2][BN][HIDN] bf16 exchange (LLC)
    u16*         __restrict__ Hb,    // [BT][HIDN] bf16 output
    u32*                      bar)   // counters (stride 64), zeroed per launch
{
    __shared__ uint4 Wl4[4 * 512];       // 32 KB: [ct][8 q][64 l][8] u16
    __shared__ float gl[4][16][16];      // 4 KB gate exchange

    const int tid  = threadIdx.x;
    const int rg   = blockIdx.x >> 4;    // row group: batch rows rg*16..+15
    const int ns   = blockIdx.x & 15;    // unit slice: units ns*16..+15
    const int u0   = ns * 16;
    const int w    = tid >> 6;           // wave = gate type (i,j,f,o)
    const int lane = tid & 63;
    const int m    = lane & 15, kq = lane >> 4;

    {   // load W_h slice: tiles c = w'*16 + ns, 8 KB contiguous each
        const uint4* src = (const uint4*)Whf;
        #pragma unroll
        for (int i = 0; i < 8; ++i) {
            int e  = tid + i * 256;          // [0, 2048)
            int ct = e >> 9, off = e & 511;  // 512 uint4 per tile
            Wl4[e] = src[(size_t)(ct * 16 + ns) * 512 + off];
        }
    }
    {   // zero gate-exchange so t=0 reads 0 for the h@W_h term
        float* g0 = (float*)gl;
        #pragma unroll
        for (int j = 0; j < 4; ++j) g0[tid * 4 + j] = 0.0f;
    }
    __syncthreads();

    const u16* Wl = (const u16*)Wl4;

    const int r = tid >> 4, u = tid & 15;
    const int b = rg * 16 + r;                       // batch row
    const float* gxp = gx + (size_t)b * TN * GATES + u0 + u;
    u16* hbp = Hb + (size_t)b * TN * HIDN + u0 + u;
    const int hxw = b * HIDN + u0 + u;               // Hx elem offset (in-buf)
    const int aoff = (rg * 16 + m) * HIDN + kq * 8;  // a-frag elem offset

    float cstate = 0.0f;
    float4 gxr;
    gxr.x = gxp[0]; gxr.y = gxp[256]; gxr.z = gxp[512]; gxr.w = gxp[768];

    for (int t = 0; t < TN; ++t) {
        // prefetch next step's x-gates early (hide HBM latency behind MFMA)
        float4 gxn = gxr;
        if (t + 1 < TN) {
            const float* p = gxp + (size_t)(t + 1) * GATES;
            gxn.x = p[0]; gxn.y = p[256]; gxn.z = p[512]; gxn.w = p[768];
        }

        if (t > 0) {
            // a-frags from LLC: relaxed agent u64 atomic loads (sc0 sc1)
            const u64* hsrc = (const u64*)(Hx + (t & 1) * (BN * HIDN) + aoff);
            v4f acc = {0.f, 0.f, 0.f, 0.f};
            #pragma unroll
            for (int q = 0; q < 8; ++q) {
                union { u64 d[2]; v8s v; } av;
                av.d[0] = llc_load(hsrc + q * 8);
                av.d[1] = llc_load(hsrc + q * 8 + 1);
                v8s bf = *(const v8s*)(Wl + ((w * 8 + q) * 64 + lane) * 8);
                acc = __builtin_amdgcn_mfma_f32_16x16x32_bf16(av.v, bf, acc, 0, 0, 0);
            }
            #pragma unroll
            for (int rr = 0; rr < 4; ++rr)   // row = kq*4+rr, col(unit) = m
                gl[w][kq * 4 + rr][m] = acc[rr];
        }
        __syncthreads();

        {   // cell update for (r, u); c stays in a register
            float ai = gl[0][r][u] + gxr.x;
            float aj = gl[1][r][u] + gxr.y;
            float af = gl[2][r][u] + gxr.z;
            float ao = gl[3][r][u] + gxr.w;
            float ig = fast_sigmoid(ai);
            float fg = fast_sigmoid(af + 1.0f);      // forget_bias = 1.0
            float og = fast_sigmoid(ao);
            float jt = fast_tanh(aj);
            cstate = fg * cstate + ig * jt;
            float hn = og * fast_tanh(cstate);
            u32 hv = f2bf(hn);
            hbp[(size_t)t * HIDN] = (u16)hv;

            if (t + 1 < TN) {
                // pack 4 consecutive units (same row, lanes tid..tid+3) into
                // one u64 and publish via relaxed agent atomic store -> LLC
                u32 p1 = __shfl_down(hv, 1);
                u32 p2 = __shfl_down(hv, 2);
                u32 p3 = __shfl_down(hv, 3);
                if ((tid & 3) == 0) {
                    u64 pk = (u64)(hv | (p1 << 16))
                           | ((u64)(p2 | (p3 << 16)) << 32);
                    u64* dst = (u64*)(Hx + (((t & 1) ^ 1) * (BN * HIDN)) + hxw);
                    llc_store(dst, pk);
                }
            }
        }

        if (t + 1 < TN) {
            __syncthreads();   // per-wave vmcnt(0) before s_barrier: all
                               // publish stores have reached the LLC
            if (tid == 0) {
                __hip_atomic_fetch_add(&bar[rg * 64], 1u, __ATOMIC_RELAXED,
                                       __HIP_MEMORY_SCOPE_AGENT);
                u32 tgt = (u32)(t + 1) * 16u;
                while (__hip_atomic_load(&bar[rg * 64], __ATOMIC_RELAXED,
                                         __HIP_MEMORY_SCOPE_AGENT) < tgt)
                    __builtin_amdgcn_s_sleep(1);
            }
            __syncthreads();   // broadcast release; also orders next gl writes
        }
        gxr = gxn;
    }
}

// ---------------------------------------------------------------------------
// Kernel 3 (MFMA dense, 4-way vocab split — the ONE change vs the 423us
// base): 256 blocks = 64 row-groups(64 rows, 4 register-resident a-frag
// row-tiles) x 4 vocab quarters (~157 tiles = 1.28 MB Wf each; fits an XCD
// L2, and with round-robin blockIdx%8->XCD, hv=bid&3 gives each XCD a single
// quarter — perf-only assumption, G16-safe). 32 MFMA per 8 b-frag loads;
// total Wf traffic halves vs the 2-row-tile version (655 -> 328 MB).
// No running max: |logit| small, exp never overflows fp32.
// ---------------------------------------------------------------------------
__global__ __launch_bounds__(256, 1) void k_dense(
    const u16*   __restrict__ Hb,    // [BT][HIDN] bf16
    const u16*   __restrict__ Wf,    // [625][8][64][8]
    const float* __restrict__ bd,    // [VOCAB]
    float*       __restrict__ S)     // [4][BT] partial sumexp
{
    __shared__ float Sl[64];
    const int bid = blockIdx.x;
    const int hv  = bid & 3;                    // vocab quarter (XCD-aligned)
    const int rg  = bid >> 2;                   // 0..63
    const int r0  = rg * 64;
    const int tid = threadIdx.x;
    const int w   = tid >> 6, lane = tid & 63;
    const int m   = lane & 15, kq = lane >> 4;

    if (tid < 64) Sl[tid] = 0.0f;

    v8s a[4][8];
    #pragma unroll
    for (int rt = 0; rt < 4; ++rt) {
        const u16* hrow = Hb + (size_t)(r0 + rt * 16 + m) * HIDN + kq * 8;
        #pragma unroll
        for (int q = 0; q < 8; ++q)
            a[rt][q] = *(const v8s*)(hrow + q * 32);
    }
    __syncthreads();

    float s[4][4] = {{0.f,0.f,0.f,0.f},{0.f,0.f,0.f,0.f},
                     {0.f,0.f,0.f,0.f},{0.f,0.f,0.f,0.f}};
    const int cbeg = (hv * NCT) >> 2;
    const int cend = ((hv + 1) * NCT) >> 2;
    for (int c = cbeg + w; c < cend; c += 4) {
        v4f acc[4] = {{0.f,0.f,0.f,0.f},{0.f,0.f,0.f,0.f},
                      {0.f,0.f,0.f,0.f},{0.f,0.f,0.f,0.f}};
        #pragma unroll
        for (int q = 0; q < 8; ++q) {
            v8s bq = *(const v8s*)(Wf + (((size_t)c * 8 + q) * 64 + lane) * 8);
            #pragma unroll
            for (int rt = 0; rt < 4; ++rt)
                acc[rt] = __builtin_amdgcn_mfma_f32_16x16x32_bf16(
                              a[rt][q], bq, acc[rt], 0, 0, 0);
        }
        const float bv = bd[c * 16 + m];
        #pragma unroll
        for (int rt = 0; rt < 4; ++rt)
            #pragma unroll
            for (int r = 0; r < 4; ++r)
                s[rt][r] += __expf(acc[rt][r] + bv);
    }

    #pragma unroll
    for (int rt = 0; rt < 4; ++rt)
        #pragma unroll
        for (int r = 0; r < 4; ++r)
            atomicAdd(&Sl[rt * 16 + kq * 4 + r], s[rt][r]);
    __syncthreads();
    if (tid < 64) S[(size_t)hv * BT + r0 + tid] = Sl[tid];
}

// ---------------------------------------------------------------------------
// Kernel 4: target logit per row (direct dot from bf16 frags). 32 thr/row.
// ---------------------------------------------------------------------------
__global__ __launch_bounds__(256) void k_target(
    const u16*   __restrict__ Hb,
    const u16*   __restrict__ Wf,
    const float* __restrict__ bd,
    const int*   __restrict__ tgt,
    float*       __restrict__ tl)    // [BT]
{
    const int tid = threadIdx.x;
    const int row = blockIdx.x * 8 + (tid >> 5);
    const int t   = tid & 31;
    const int q   = t >> 2, lq = t & 3;
    const int v   = tgt[row];
    const int c   = v >> 4, vm = v & 15;
    const int kb  = q * 32 + lq * 8;

    v8s h  = *(const v8s*)(Hb + (size_t)row * HIDN + kb);
    v8s wv = *(const v8s*)(Wf + (((size_t)c * 8 + q) * 64 + lq * 16 + vm) * 8);
    float acc = 0.0f;
    #pragma unroll
    for (int j = 0; j < 8; ++j)
        acc = fmaf(bf2f((u16)h[j]), bf2f((u16)wv[j]), acc);
    #pragma unroll
    for (int off = 16; off >= 1; off >>= 1)
        acc += __shfl_down(acc, off, 32);
    if (t == 0) tl[row] = acc + bd[v];
}

// ---------------------------------------------------------------------------
// Kernel 5: ppl = exp(log(sum of 4 partial sumexp) - target_logit)
// ---------------------------------------------------------------------------
__global__ __launch_bounds__(256) void k_final(
    const float* __restrict__ S,     // [4][BT]
    const float* __restrict__ tl,    // [BT]
    float*       __restrict__ out)   // [BT]
{
    int i = blockIdx.x * 256 + threadIdx.x;
    float sum = S[i] + S[BT + i] + S[2 * BT + i] + S[3 * BT + i];
    out[i] = __expf(__logf(sum) - tl[i]);
}

// ---------------------------------------------------------------------------
extern "C" void kernel_launch(void* const* d_in, const int* in_sizes, int n_in,
                              void* d_out, int out_size, void* d_ws, size_t ws_size,
                              hipStream_t stream) {
    const int*   input   = (const int*)  d_in[0];   // [B,T]
    const int*   targets = (const int*)  d_in[1];   // [B,T]
    const float* E       = (const float*)d_in[2];   // [VOCAB,HID]
    const float* W_lstm  = (const float*)d_in[3];   // [2H,4H]
    const float* b_lstm  = (const float*)d_in[4];   // [4H]
    const float* W_dense = (const float*)d_in[5];   // [HID,VOCAB]
    const float* b_dense = (const float*)d_in[6];   // [VOCAB]
    float* out = (float*)d_out;                     // [B,T] perplexity

    // Workspace (< 19.3 MB; 20 MB proven in earlier rounds):
    //  [0,16M):            gx fp32 [BT][GATES]; Wf (5.12 MB) reuses this
    //                      region after k_plstm consumes gx — stream-ordered.
    //  [16M,18M):          Hb bf16 [BT][HIDN]
    //  [18M,+512K):        Whf (h-part frags)
    //  [18.5M,+512K):      Wxf (x-part frags)
    //  [19M,+64K):         Hx bf16 [2][BN][HIDN] exchange
    //  [19M+64K,+64K):     S fp32 [4][BT]
    //  [19M+128K,+16K):    tl fp32 [BT]
    //  [19M+144K,+1K):     bar u32 [4*64] (256B-strided counters)
    char* ws = (char*)d_ws;
    float* gx  = (float*)ws;
    u16*   Wf  = (u16*)ws;
    u16*   Hb  = (u16*)(ws + ((size_t)16 << 20));
    u16*   Whf = (u16*)(ws + ((size_t)18 << 20));
    u16*   Wxf = (u16*)(ws + ((size_t)18 << 20) + ((size_t)512 << 10));
    u16*   Hx  = (u16*)(ws + ((size_t)19 << 20));
    float* S   = (float*)(ws + ((size_t)19 << 20) + ((size_t)64 << 10));
    float* tl  = (float*)(ws + ((size_t)19 << 20) + ((size_t)128 << 10));
    u32*   bar = (u32*)  (ws + ((size_t)19 << 20) + ((size_t)144 << 10));

    hipMemsetAsync(bar, 0, 1024, stream);
    k_wfrag <<<64,      256, 0, stream>>>(W_lstm,                      Wxf, GATES);
    k_wfrag <<<64,      256, 0, stream>>>(W_lstm + (size_t)HIDN*GATES, Whf, GATES);
    k_xgates<<<BT / 16, 256, 0, stream>>>(input, E, Wxf, b_lstm, gx);
    k_plstm <<<64,      256, 0, stream>>>(Whf, gx, Hx, Hb, bar);
    k_wfrag <<<NCT,     256, 0, stream>>>(W_dense, Wf, VOCABN);   // reuses gx
    k_dense <<<256,     256, 0, stream>>>(Hb, Wf, b_dense, S);
    k_target<<<BT / 8,  256, 0, stream>>>(Hb, Wf, b_dense, targets, tl);
    k_final <<<BT / 256,256, 0, stream>>>(S, tl, out);
}